// Round 10
// baseline (783.195 us; speedup 1.0000x reference)
//
#include <hip/hip_runtime.h>
#include <hip/hip_bf16.h>
#include <stdint.h>
#include <stdio.h>

// Problem geometry (fixed by the reference)
#define M_DIM 8192    // 4*2048
#define K_DIM 4096    // IN_FEATURES
#define N_DIM 11008   // OUT_FEATURES

// 256^2 8-phase template (m201 structure)
#define BM 256
#define BN 256
#define BK 64
#define NT (K_DIM / BK)           // 64 K-tiles (power of 2 -> & wrap ok)
#define TILES_M (M_DIM / BM)      // 32
#define TILES_N (N_DIM / BN)      // 43
#define NWG (TILES_M * TILES_N)   // 1376

typedef __bf16 bf16x8 __attribute__((ext_vector_type(8)));
typedef float f32x4 __attribute__((ext_vector_type(4)));

__device__ __constant__ float kFp4Code[16] = {
    0.0f,           0.0052083333f,  0.6666666666f, 1.0f,
    0.3333333333f,  0.5f,           0.1666666666f, 0.25f,
    -0.0f,          -0.0052083333f, -0.6666666666f, -1.0f,
    -0.3333333333f, -0.5f,          -0.1666666666f, -0.25f
};

// ---------------------------------------------------------------------------
// Kernel 1: FP4 dequant -> bf16 W [N_DIM][K_DIM]
// ---------------------------------------------------------------------------
__global__ __launch_bounds__(256) void fp4_dequant_kernel(
    const int* __restrict__ codes, const float* __restrict__ absmax,
    __hip_bfloat16* __restrict__ w)
{
    __shared__ float lut[16];
    if (threadIdx.x < 16) lut[threadIdx.x] = kFp4Code[threadIdx.x];
    __syncthreads();

    const int t = blockIdx.x * 256 + threadIdx.x;  // < 5,636,096
    const int4* cp = (const int4*)codes;
    const int4 c0 = cp[2 * t];
    const int4 c1 = cp[2 * t + 1];
    const float am = absmax[t >> 3];

    union { int4 v; __hip_bfloat16 h[8]; } u;
    u.h[0] = __float2bfloat16(lut[c0.x & 15] * am);
    u.h[1] = __float2bfloat16(lut[c0.y & 15] * am);
    u.h[2] = __float2bfloat16(lut[c0.z & 15] * am);
    u.h[3] = __float2bfloat16(lut[c0.w & 15] * am);
    u.h[4] = __float2bfloat16(lut[c1.x & 15] * am);
    u.h[5] = __float2bfloat16(lut[c1.y & 15] * am);
    u.h[6] = __float2bfloat16(lut[c1.z & 15] * am);
    u.h[7] = __float2bfloat16(lut[c1.w & 15] * am);
    ((int4*)w)[t] = u.v;
}

// ---------------------------------------------------------------------------
// Kernel 2: x fp32 -> bf16  [M_DIM][K_DIM]
// ---------------------------------------------------------------------------
__global__ __launch_bounds__(256) void f32_to_bf16_kernel(
    const float* __restrict__ x, __hip_bfloat16* __restrict__ y)
{
    const int t = blockIdx.x * 256 + threadIdx.x;  // < 4,194,304
    const float4* xp = (const float4*)x;
    const float4 a = xp[2 * t];
    const float4 b = xp[2 * t + 1];
    union { int4 v; __hip_bfloat16 h[8]; } u;
    u.h[0] = __float2bfloat16(a.x);
    u.h[1] = __float2bfloat16(a.y);
    u.h[2] = __float2bfloat16(a.z);
    u.h[3] = __float2bfloat16(a.w);
    u.h[4] = __float2bfloat16(b.x);
    u.h[5] = __float2bfloat16(b.y);
    u.h[6] = __float2bfloat16(b.z);
    u.h[7] = __float2bfloat16(b.w);
    ((int4*)y)[t] = u.v;
}

// ---------------------------------------------------------------------------
// Kernel 3: bf16 GEMM, C = A * B^T + bias   (256x256 tile, 8-phase schedule)
//
// Round-10 change vs round-9: ds_reads moved AFTER bar#1, INTERLEAVED into
// the MFMA cluster with sched_group_barrier (T19). Round-9 arithmetic:
// window 1264 = 620 MFMA + 644 front-segment; per-K-tile LDS-pipe work
// (192 b128 reads + 64KB gload-writes ~ 2300 cyc/CU) was fully SERIALIZED
// with MFMA (2480 cyc/SIMD): 4x1264 ~= sum. Reads target FUTURE windows
// (round-8 read-ahead), so the MFMA cluster has no lgkm dependence on them;
// with placement pinned (2 MFMA, then 1 read/1 MFMA x R, then 14-R MFMA),
// the LDS queue drains under the matrix pipe, and any compiler lgkm-drain at
// bar#2 is satisfied nearly for free.
//   Read schedule (unchanged):  P0: bvHi(t)[4]  P1: avHi(t)[8]
//                               P2: avLo(t+1)[8]  P3: bvLo(t+1)[4, ping-pong]
//   Stage schedule (unchanged): P0: A-hi(t+1), P1: A-lo(t+2),
//                               P2: B-lo(t+2), P3: B-hi(t+2)
//   vmcnt(6) at P1+P3 (unchanged). Confirm ledger: reads moved later =
//   strictly safer. Overwrite ledger re-checked per pair: each read's
//   lgkm-complete (forced before its consuming MFMA) precedes the region's
//   overwriting gload issue by >=1 barrier.
// 2D brick work order (round-9, kept): per-XCD 8(m)x4(n) bricks.
// LDS (128 KiB): 2 dbuf x { A-lo@0, A-hi@16384, B-lo@32768, B-hi@49152 }.
// XOR involution swizzle (round-2-proven, 0 conflicts).
// ---------------------------------------------------------------------------
#define STAGE(gbase, eoff, loff)                                              \
    __builtin_amdgcn_global_load_lds(                                         \
        (const __attribute__((address_space(1))) void*)((gbase) + (eoff)),    \
        (__attribute__((address_space(3))) void*)(lds + (loff)), 16, 0, 0)

__device__ __forceinline__ void mfma_quad(
    f32x4 (&accq)[4][2], bf16x8 (&av)[4][2], bf16x8 (&bv)[2][2])
{
    __builtin_amdgcn_s_setprio(1);
#pragma unroll
    for (int ks = 0; ks < 2; ++ks)
#pragma unroll
        for (int m = 0; m < 4; ++m)
#pragma unroll
            for (int n = 0; n < 2; ++n)
                accq[m][n] = __builtin_amdgcn_mfma_f32_16x16x32_bf16(
                    av[m][ks], bv[n][ks], accq[m][n], 0, 0, 0);
    __builtin_amdgcn_s_setprio(0);
}

// T19 pin: emit 2 MFMA, then alternate 1 DS_READ / 1 MFMA (R times), then
// the remaining 14-R MFMAs. Masks: MFMA=0x8, DS_READ=0x100 (m137/CK).
template<int R>
__device__ __forceinline__ void sgb_interleave()
{
    __builtin_amdgcn_sched_group_barrier(0x008, 2, 0);
#pragma unroll
    for (int i = 0; i < R; ++i) {
        __builtin_amdgcn_sched_group_barrier(0x100, 1, 0);
        __builtin_amdgcn_sched_group_barrier(0x008, 1, 0);
    }
    __builtin_amdgcn_sched_group_barrier(0x008, 14 - R, 0);
}

template<int BUF>
__device__ __forceinline__ void tile_body(
    int t, f32x4 (&acc)[4][4][2],
    const __hip_bfloat16* __restrict__ A, const __hip_bfloat16* __restrict__ B,
    char* lds,
    const int (&sA_lo)[2], const int (&sA_hi)[2],
    const int (&sB_lo)[2], const int (&sB_hi)[2],
    int dst0, int dst1,
    const char* pA0, const char* pA1, const char* pB0, const char* pB1,
    bf16x8 (&avLo)[4][2], bf16x8 (&avHi)[4][2], bf16x8 (&bvHi)[2][2],
    bf16x8 (&bvLoC)[2][2], bf16x8 (&bvLoN)[2][2])
{
    constexpr int LB  = BUF * 65536;         // this tile's buffer
    constexpr int LB1 = (BUF ^ 1) * 65536;   // (t+1)'s buffer
    const int koff1 = ((t + 1) & (NT - 1)) * 64;   // wave-uniform (SALU)
    const int koff2 = ((t + 2) & (NT - 1)) * 64;

    // ---- P0: stage A-hi(t+1); bar; {read bvHi(t) ∥ MFMA Q(0,0)} ----
    STAGE(A, sA_hi[0] + koff1, LB1 + 16384 + dst0);
    STAGE(A, sA_hi[1] + koff1, LB1 + 16384 + dst1);
    __builtin_amdgcn_s_barrier();
#pragma unroll
    for (int n = 0; n < 2; ++n) {
        bvHi[n][0] = *(const bf16x8*)(pB0 + LB + 16384 + n * 2048);
        bvHi[n][1] = *(const bf16x8*)(pB1 + LB + 16384 + n * 2048);
    }
    mfma_quad(acc[0], avLo, bvLoC);
    sgb_interleave<4>();
    __builtin_amdgcn_s_barrier();

    // ---- P1: stage A-lo(t+2); vmcnt(6) [confirms A-lo(t+1),B-lo(t+1)];
    //      bar; {read avHi(t) ∥ MFMA Q(0,1)} ----
    STAGE(A, sA_lo[0] + koff2, LB + dst0);
    STAGE(A, sA_lo[1] + koff2, LB + dst1);
    asm volatile("s_waitcnt vmcnt(6)" ::: "memory");
    __builtin_amdgcn_s_barrier();
#pragma unroll
    for (int m = 0; m < 4; ++m) {
        avHi[m][0] = *(const bf16x8*)(pA0 + LB + 16384 + m * 2048);
        avHi[m][1] = *(const bf16x8*)(pA1 + LB + 16384 + m * 2048);
    }
    mfma_quad(acc[1], avLo, bvHi);
    sgb_interleave<8>();
    __builtin_amdgcn_s_barrier();

    // ---- P2: stage B-lo(t+2); bar; {read avLo(t+1) ∥ MFMA Q(1,1)} ----
    STAGE(B, sB_lo[0] + koff2, LB + 32768 + dst0);
    STAGE(B, sB_lo[1] + koff2, LB + 32768 + dst1);
    __builtin_amdgcn_s_barrier();
#pragma unroll
    for (int m = 0; m < 4; ++m) {
        avLo[m][0] = *(const bf16x8*)(pA0 + LB1 + m * 2048);
        avLo[m][1] = *(const bf16x8*)(pA1 + LB1 + m * 2048);
    }
    mfma_quad(acc[2], avHi, bvHi);
    sgb_interleave<8>();
    __builtin_amdgcn_s_barrier();

    // ---- P3: stage B-hi(t+2); vmcnt(6) [confirms B-hi(t+1),A-hi(t+1)];
    //      bar; {read bvLo(t+1) ∥ MFMA Q(1,0)} ----
    STAGE(B, sB_hi[0] + koff2, LB + 49152 + dst0);
    STAGE(B, sB_hi[1] + koff2, LB + 49152 + dst1);
    asm volatile("s_waitcnt vmcnt(6)" ::: "memory");
    __builtin_amdgcn_s_barrier();
#pragma unroll
    for (int n = 0; n < 2; ++n) {
        bvLoN[n][0] = *(const bf16x8*)(pB0 + LB1 + n * 2048);
        bvLoN[n][1] = *(const bf16x8*)(pB1 + LB1 + n * 2048);
    }
    mfma_quad(acc[3], avHi, bvLoC);
    sgb_interleave<4>();
    __builtin_amdgcn_s_barrier();
}

__global__ __launch_bounds__(512, 2) void gemm_bf16_8phase(
    const __hip_bfloat16* __restrict__ A, const __hip_bfloat16* __restrict__ B,
    const float* __restrict__ bias, float* __restrict__ C)
{
    extern __shared__ char lds[];  // 131072 B

    const int tid = threadIdx.x;
    const int lane = tid & 63;
    const int wid = tid >> 6;       // 0..7
    const int wr = wid >> 2;        // 0..1 (M split)
    const int wc = wid & 3;         // 0..3 (N split)
    const int l15 = lane & 15;
    const int kgrp = lane >> 4;

    // XCD stripe (bijective) + 2D brick order (round-9): per-XCD 8x4 bricks.
    const int wg = blockIdx.x;
    const int s = (wg & 7) * (NWG / 8) + (wg >> 3);
    int bm, bn;
    if (s < 1280) {                 // 10 groups of width 4 (8x4 bricks)
        const int g = s >> 7;
        const int j = s & 127;
        bm = j >> 2;
        bn = g * 4 + (j & 3);
    } else {                        // last group: width 3
        const int j = s - 1280;     // 0..95
        bm = j / 3;
        bn = 40 + j % 3;
    }
    const int m0 = bm * BM;
    const int n0 = bn * BN;

    // ---- Precomputed stage-source element offsets (per lane, once) ----
    int sA_lo[2], sA_hi[2], sB_lo[2], sB_hi[2];
#pragma unroll
    for (int c = 0; c < 2; ++c) {
        const int idx = c * 512 + tid;          // 0..1023 chunk id (linear LDS)
        const int row = idx >> 3;               // 0..127
        const int scol = (idx & 7) ^ (row & 7); // pre-swizzled source chunk
        sA_lo[c] = (m0 + row) * K_DIM + scol * 8;
        sA_hi[c] = sA_lo[c] + 128 * K_DIM;
        sB_lo[c] = (n0 + row) * K_DIM + scol * 8;
        sB_hi[c] = sB_lo[c] + 128 * K_DIM;
    }
    const int dst0 = wid * 1024;          // (c*512 + wid*64)*16, c=0
    const int dst1 = 8192 + wid * 1024;   // c=1

    // ---- Precomputed fragment-read base pointers (buf0; buf1 = +65536) ----
    const int xlo = l15 & 7;
    const char* pA0 = lds + (wr * 64 + l15) * 128 + ((kgrp) ^ xlo) * 16;
    const char* pA1 = lds + (wr * 64 + l15) * 128 + ((4 + kgrp) ^ xlo) * 16;
    const char* pB0 = lds + 32768 + (wc * 32 + l15) * 128 + ((kgrp) ^ xlo) * 16;
    const char* pB1 = lds + 32768 + (wc * 32 + l15) * 128 + ((4 + kgrp) ^ xlo) * 16;

    // acc quadrants: 0=(0,0) 1=(0,1) 2=(1,1) 3=(1,0)  (mq,nq)
    f32x4 acc[4][4][2];
#pragma unroll
    for (int q = 0; q < 4; ++q)
#pragma unroll
        for (int m = 0; m < 4; ++m)
#pragma unroll
            for (int n = 0; n < 2; ++n)
                acc[q][m][n] = (f32x4){0.f, 0.f, 0.f, 0.f};

    // Fragment registers (live across tile_body calls)
    bf16x8 avLo[4][2], avHi[4][2], bvHi[2][2], bvLoA[2][2], bvLoB[2][2];

    // Prologue: 7 halves, FIFO order matching steady state:
    // A-lo(0), B-lo(0), B-hi(0), A-hi(0), A-lo(1), B-lo(1), B-hi(1)
    STAGE(A, sA_lo[0], dst0);                 STAGE(A, sA_lo[1], dst1);
    STAGE(B, sB_lo[0], 32768 + dst0);         STAGE(B, sB_lo[1], 32768 + dst1);
    STAGE(B, sB_hi[0], 49152 + dst0);         STAGE(B, sB_hi[1], 49152 + dst1);
    STAGE(A, sA_hi[0], 16384 + dst0);         STAGE(A, sA_hi[1], 16384 + dst1);
    STAGE(A, sA_lo[0] + 64, 65536 + dst0);    STAGE(A, sA_lo[1] + 64, 65536 + dst1);
    STAGE(B, sB_lo[0] + 64, 98304 + dst0);    STAGE(B, sB_lo[1] + 64, 98304 + dst1);
    STAGE(B, sB_hi[0] + 64, 114688 + dst0);   STAGE(B, sB_hi[1] + 64, 114688 + dst1);
    asm volatile("s_waitcnt vmcnt(6)" ::: "memory"); // tile-0's 4 halves landed
    __builtin_amdgcn_s_barrier();

    // Prologue prefetch-reads (the P2(-1)/P3(-1) slots): avLo(0), bvLoA(0)
#pragma unroll
    for (int m = 0; m < 4; ++m) {
        avLo[m][0] = *(const bf16x8*)(pA0 + m * 2048);
        avLo[m][1] = *(const bf16x8*)(pA1 + m * 2048);
    }
#pragma unroll
    for (int n = 0; n < 2; ++n) {
        bvLoA[n][0] = *(const bf16x8*)(pB0 + n * 2048);
        bvLoA[n][1] = *(const bf16x8*)(pB1 + n * 2048);
    }

    for (int t = 0; t < NT; t += 2) {
        tile_body<0>(t,     acc, A, B, lds, sA_lo, sA_hi, sB_lo, sB_hi,
                     dst0, dst1, pA0, pA1, pB0, pB1,
                     avLo, avHi, bvHi, bvLoA, bvLoB);
        tile_body<1>(t + 1, acc, A, B, lds, sA_lo, sA_hi, sB_lo, sB_hi,
                     dst0, dst1, pA0, pA1, pB0, pB1,
                     avLo, avHi, bvHi, bvLoB, bvLoA);
    }

    // Epilogue (C/D layout: col = lane&15, row = (lane>>4)*4 + reg).
#pragma unroll
    for (int q = 0; q < 4; ++q) {
        const int mqe = q >> 1;
        const int nqe = (q == 1 || q == 2) ? 1 : 0;
#pragma unroll
        for (int n = 0; n < 2; ++n) {
            const int col = n0 + nqe * 128 + wc * 32 + n * 16 + l15;
            const float bval = bias[col];
#pragma unroll
            for (int m = 0; m < 4; ++m) {
                const int row = m0 + mqe * 128 + wr * 64 + m * 16 + kgrp * 4;
#pragma unroll
                for (int r = 0; r < 4; ++r)
                    __builtin_nontemporal_store(acc[q][m][n][r] + bval,
                        &C[(size_t)(row + r) * N_DIM + col]);
            }
        }
    }
}

// ---------------------------------------------------------------------------
extern "C" void kernel_launch(void* const* d_in, const int* in_sizes, int n_in,
                              void* d_out, int out_size, void* d_ws, size_t ws_size,
                              hipStream_t stream)
{
    const float* x      = (const float*)d_in[0];  // [4,2048,4096] f32
    const int*   codes  = (const int*)d_in[1];    // [704512,64] i32
    const float* absmax = (const float*)d_in[2];  // [704512] f32
    const float* bias   = (const float*)d_in[3];  // [11008] f32
    float* out = (float*)d_out;                   // [4,2048,11008] f32

    const size_t w_bytes = (size_t)N_DIM * K_DIM * sizeof(__hip_bfloat16);
    const size_t x_bytes = (size_t)M_DIM * K_DIM * sizeof(__hip_bfloat16);
    if (ws_size < w_bytes + x_bytes) {
        fprintf(stderr, "kernel_launch: ws_size=%zu < needed %zu\n",
                ws_size, w_bytes + x_bytes);
        return;
    }
    __hip_bfloat16* wbf = (__hip_bfloat16*)d_ws;
    __hip_bfloat16* xbf = (__hip_bfloat16*)((char*)d_ws + w_bytes);

    // Allow 128 KiB dynamic LDS (idempotent host-side call; capture-safe).
    hipFuncSetAttribute((const void*)gemm_bf16_8phase,
                        hipFuncAttributeMaxDynamicSharedMemorySize, 131072);

    fp4_dequant_kernel<<<dim3(22016), dim3(256), 0, stream>>>(codes, absmax, wbf);
    f32_to_bf16_kernel<<<dim3(16384), dim3(256), 0, stream>>>(x, xbf);
    gemm_bf16_8phase<<<dim3(NWG), dim3(512), 131072, stream>>>(xbf, wbf, bias, out);
}

// Round 11
// 724.276 us; speedup vs baseline: 1.0813x; 1.0813x over previous
//
#include <hip/hip_runtime.h>
#include <hip/hip_bf16.h>
#include <stdint.h>
#include <stdio.h>

// Problem geometry (fixed by the reference)
#define M_DIM 8192    // 4*2048
#define K_DIM 4096    // IN_FEATURES
#define N_DIM 11008   // OUT_FEATURES

#define BM 256
#define BN 256
#define BK 64
#define NT (K_DIM / BK)           // 64 K-tiles (power of 2 -> & wrap ok)
#define TILES_M (M_DIM / BM)      // 32
#define TILES_N (N_DIM / BN)      // 43
#define NWG (TILES_M * TILES_N)   // 1376

typedef __bf16 bf16x8 __attribute__((ext_vector_type(8)));
typedef float f32x4 __attribute__((ext_vector_type(4)));

__device__ __constant__ float kFp4Code[16] = {
    0.0f,           0.0052083333f,  0.6666666666f, 1.0f,
    0.3333333333f,  0.5f,           0.1666666666f, 0.25f,
    -0.0f,          -0.0052083333f, -0.6666666666f, -1.0f,
    -0.3333333333f, -0.5f,          -0.1666666666f, -0.25f
};

// ---------------------------------------------------------------------------
// Kernel 1: FP4 dequant -> bf16 W [N_DIM][K_DIM]
// ---------------------------------------------------------------------------
__global__ __launch_bounds__(256) void fp4_dequant_kernel(
    const int* __restrict__ codes, const float* __restrict__ absmax,
    __hip_bfloat16* __restrict__ w)
{
    __shared__ float lut[16];
    if (threadIdx.x < 16) lut[threadIdx.x] = kFp4Code[threadIdx.x];
    __syncthreads();

    const int t = blockIdx.x * 256 + threadIdx.x;  // < 5,636,096
    const int4* cp = (const int4*)codes;
    const int4 c0 = cp[2 * t];
    const int4 c1 = cp[2 * t + 1];
    const float am = absmax[t >> 3];

    union { int4 v; __hip_bfloat16 h[8]; } u;
    u.h[0] = __float2bfloat16(lut[c0.x & 15] * am);
    u.h[1] = __float2bfloat16(lut[c0.y & 15] * am);
    u.h[2] = __float2bfloat16(lut[c0.z & 15] * am);
    u.h[3] = __float2bfloat16(lut[c0.w & 15] * am);
    u.h[4] = __float2bfloat16(lut[c1.x & 15] * am);
    u.h[5] = __float2bfloat16(lut[c1.y & 15] * am);
    u.h[6] = __float2bfloat16(lut[c1.z & 15] * am);
    u.h[7] = __float2bfloat16(lut[c1.w & 15] * am);
    ((int4*)w)[t] = u.v;
}

// ---------------------------------------------------------------------------
// Kernel 2: x fp32 -> bf16  [M_DIM][K_DIM]
// ---------------------------------------------------------------------------
__global__ __launch_bounds__(256) void f32_to_bf16_kernel(
    const float* __restrict__ x, __hip_bfloat16* __restrict__ y)
{
    const int t = blockIdx.x * 256 + threadIdx.x;  // < 4,194,304
    const float4* xp = (const float4*)x;
    const float4 a = xp[2 * t];
    const float4 b = xp[2 * t + 1];
    union { int4 v; __hip_bfloat16 h[8]; } u;
    u.h[0] = __float2bfloat16(a.x);
    u.h[1] = __float2bfloat16(a.y);
    u.h[2] = __float2bfloat16(a.z);
    u.h[3] = __float2bfloat16(a.w);
    u.h[4] = __float2bfloat16(b.x);
    u.h[5] = __float2bfloat16(b.y);
    u.h[6] = __float2bfloat16(b.z);
    u.h[7] = __float2bfloat16(b.w);
    ((int4*)y)[t] = u.v;
}

// ---------------------------------------------------------------------------
// Kernel 3: bf16 GEMM, C = A * B^T + bias  (256x256 tile, TWO windows/K-tile)
//
// Round-11 change vs round-9/10: MERGE 4 windows -> 2 per K-tile (32-MFMA
// clusters, 4 barrier-crossings/tile instead of 8). Evidence: tile time
// 5056 cyc fits MFMA(2480) + 8 barriers x ~300 cyc; every in-window
// scheduling variant (rounds 5-8, 10) was null/regressive -> the barrier
// convoy, not LDS/MFMA serialization, is the prime suspect. AITER runs ~32
// MFMA/barrier; we ran 8. This halves the barrier count.
//
// Window structure (tile t, buf LB = (t&1)*64KB, LB1 = other):
//  W0: stage {A-hi,B-hi}(t+1)->LB1; read avLo,bvLo(t) [12 b128]; vmcnt(8);
//      bar; SCHED_BARRIER(0); MFMA Q00 x16; read bvHi(t) [4]; MFMA Q01 x16;
//      bar.
//  W1: stage {A-lo,B-lo}(t+2)->LB;  read avHi(t) [8];       vmcnt(8);
//      bar; SCHED_BARRIER(0); MFMA Q11 x16;                 MFMA Q10 x16;
//      bar.
// vmcnt ledger (pair-stream FIFO, 4 gloads/pair, 12 in flight at each wait):
//  vmcnt(8) at W0(t) confirms pair{Ahi,Bhi}(t) (issued W0(t-1));
//  vmcnt(8) at W1(t) confirms pair{Alo,Blo}(t+1) (issued W1(t-1)).
// Cross-wave read safety (confirmation must be vmcnt+BARRIER in ALL waves
// before the read): avLo/bvLo(t): confirmed at W1(t-1) -> pre-bar read OK.
//  avHi(t): confirmed at W0(t) bar#1 -> W1 pre-bar read OK.
//  bvHi(t): confirmed only at W0(t) bar#1 -> read MID-CLUSTER (after bar#1);
//  sched_barrier(0) right after bar#1 prevents the scheduler hoisting it
//  above the barrier (s_barrier is not an LLVM memory fence).
// Overwrite ledger (>=1 barrier between last consume and overwriting issue):
//  Alo/Blo(t) consumed < bar#2(W0(t)); overwritten by W1(t) stage ✓.
//  Ahi(t-1) consumed < bar#2(W1(t-1)); overwritten by W0(t) stage ✓.
//  Bhi(t-1) consumed < bar#2(W0(t-1)); overwritten by W0(t) stage ✓.
// 2D brick work order (round-9 win, kept). XOR involution swizzle (round-2,
// 0 conflicts). LDS 128KB: 2 dbuf x {A-lo@0,A-hi@16K,B-lo@32K,B-hi@48K}.
// ---------------------------------------------------------------------------
#define STAGE(gbase, eoff, loff)                                              \
    __builtin_amdgcn_global_load_lds(                                         \
        (const __attribute__((address_space(1))) void*)((gbase) + (eoff)),    \
        (__attribute__((address_space(3))) void*)(lds + (loff)), 16, 0, 0)

// 16 MFMAs: one quadrant (4m x 2n x 2ks), ks-outer for dependence distance 8
__device__ __forceinline__ void mfma_half(
    f32x4 (&accq)[4][2], bf16x8 (&av)[4][2], bf16x8 (&bv)[2][2])
{
#pragma unroll
    for (int ks = 0; ks < 2; ++ks)
#pragma unroll
        for (int m = 0; m < 4; ++m)
#pragma unroll
            for (int n = 0; n < 2; ++n)
                accq[m][n] = __builtin_amdgcn_mfma_f32_16x16x32_bf16(
                    av[m][ks], bv[n][ks], accq[m][n], 0, 0, 0);
}

template<int BUF>
__device__ __forceinline__ void tile_body(
    int t, f32x4 (&acc)[4][4][2],
    const __hip_bfloat16* __restrict__ A, const __hip_bfloat16* __restrict__ B,
    char* lds,
    const int (&sA_lo)[2], const int (&sA_hi)[2],
    const int (&sB_lo)[2], const int (&sB_hi)[2],
    int dst0, int dst1,
    const char* pA0, const char* pA1, const char* pB0, const char* pB1)
{
    constexpr int LB  = BUF * 65536;         // this tile's buffer
    constexpr int LB1 = (BUF ^ 1) * 65536;   // (t+1)'s buffer
    const int koff1 = ((t + 1) & (NT - 1)) * 64;   // wave-uniform (SALU)
    const int koff2 = ((t + 2) & (NT - 1)) * 64;

    bf16x8 avLo[4][2], avHi[4][2], bvLo[2][2], bvHi[2][2];

    // ================= W0 =================
    STAGE(A, sA_hi[0] + koff1, LB1 + 16384 + dst0);
    STAGE(A, sA_hi[1] + koff1, LB1 + 16384 + dst1);
    STAGE(B, sB_hi[0] + koff1, LB1 + 49152 + dst0);
    STAGE(B, sB_hi[1] + koff1, LB1 + 49152 + dst1);
    // pre-bar reads (cross-wave-confirmed at W1(t-1) vmcnt+bar)
#pragma unroll
    for (int m = 0; m < 4; ++m) {
        avLo[m][0] = *(const bf16x8*)(pA0 + LB + m * 2048);
        avLo[m][1] = *(const bf16x8*)(pA1 + LB + m * 2048);
    }
#pragma unroll
    for (int n = 0; n < 2; ++n) {
        bvLo[n][0] = *(const bf16x8*)(pB0 + LB + n * 2048);
        bvLo[n][1] = *(const bf16x8*)(pB1 + LB + n * 2048);
    }
    asm volatile("s_waitcnt vmcnt(8)" ::: "memory");
    __builtin_amdgcn_s_barrier();
    __builtin_amdgcn_sched_barrier(0);     // nothing crosses bar#1
    __builtin_amdgcn_s_setprio(1);
    mfma_half(acc[0], avLo, bvLo);         // Q(0,0)
    // mid-cluster read: bvHi(t) is cross-wave-safe only after bar#1(W0(t))
#pragma unroll
    for (int n = 0; n < 2; ++n) {
        bvHi[n][0] = *(const bf16x8*)(pB0 + LB + 16384 + n * 2048);
        bvHi[n][1] = *(const bf16x8*)(pB1 + LB + 16384 + n * 2048);
    }
    mfma_half(acc[1], avLo, bvHi);         // Q(0,1)
    __builtin_amdgcn_s_setprio(0);
    __builtin_amdgcn_s_barrier();

    // ================= W1 =================
    STAGE(A, sA_lo[0] + koff2, LB + dst0);
    STAGE(A, sA_lo[1] + koff2, LB + dst1);
    STAGE(B, sB_lo[0] + koff2, LB + 32768 + dst0);
    STAGE(B, sB_lo[1] + koff2, LB + 32768 + dst1);
    // pre-bar read avHi(t) (cross-wave-confirmed at W0(t) bar#1)
#pragma unroll
    for (int m = 0; m < 4; ++m) {
        avHi[m][0] = *(const bf16x8*)(pA0 + LB + 16384 + m * 2048);
        avHi[m][1] = *(const bf16x8*)(pA1 + LB + 16384 + m * 2048);
    }
    asm volatile("s_waitcnt vmcnt(8)" ::: "memory");
    __builtin_amdgcn_s_barrier();
    __builtin_amdgcn_sched_barrier(0);
    __builtin_amdgcn_s_setprio(1);
    mfma_half(acc[2], avHi, bvHi);         // Q(1,1)
    mfma_half(acc[3], avHi, bvLo);         // Q(1,0)
    __builtin_amdgcn_s_setprio(0);
    __builtin_amdgcn_s_barrier();
}

__global__ __launch_bounds__(512, 2) void gemm_bf16_8phase(
    const __hip_bfloat16* __restrict__ A, const __hip_bfloat16* __restrict__ B,
    const float* __restrict__ bias, float* __restrict__ C)
{
    extern __shared__ char lds[];  // 131072 B

    const int tid = threadIdx.x;
    const int lane = tid & 63;
    const int wid = tid >> 6;       // 0..7
    const int wr = wid >> 2;        // 0..1 (M split)
    const int wc = wid & 3;         // 0..3 (N split)
    const int l15 = lane & 15;
    const int kgrp = lane >> 4;

    // XCD stripe (bijective) + 2D brick order (round-9): per-XCD 8x4 bricks.
    const int wg = blockIdx.x;
    const int s = (wg & 7) * (NWG / 8) + (wg >> 3);
    int bm, bn;
    if (s < 1280) {                 // 10 groups of width 4 (8x4 bricks)
        const int g = s >> 7;
        const int j = s & 127;
        bm = j >> 2;
        bn = g * 4 + (j & 3);
    } else {                        // last group: width 3
        const int j = s - 1280;     // 0..95
        bm = j / 3;
        bn = 40 + j % 3;
    }
    const int m0 = bm * BM;
    const int n0 = bn * BN;

    // ---- Precomputed stage-source element offsets (per lane, once) ----
    int sA_lo[2], sA_hi[2], sB_lo[2], sB_hi[2];
#pragma unroll
    for (int c = 0; c < 2; ++c) {
        const int idx = c * 512 + tid;          // 0..1023 chunk id (linear LDS)
        const int row = idx >> 3;               // 0..127
        const int scol = (idx & 7) ^ (row & 7); // pre-swizzled source chunk
        sA_lo[c] = (m0 + row) * K_DIM + scol * 8;
        sA_hi[c] = sA_lo[c] + 128 * K_DIM;
        sB_lo[c] = (n0 + row) * K_DIM + scol * 8;
        sB_hi[c] = sB_lo[c] + 128 * K_DIM;
    }
    const int dst0 = wid * 1024;          // (c*512 + wid*64)*16, c=0
    const int dst1 = 8192 + wid * 1024;   // c=1

    // ---- Precomputed fragment-read base pointers (buf0; buf1 = +65536) ----
    const int xlo = l15 & 7;
    const char* pA0 = lds + (wr * 64 + l15) * 128 + ((kgrp) ^ xlo) * 16;
    const char* pA1 = lds + (wr * 64 + l15) * 128 + ((4 + kgrp) ^ xlo) * 16;
    const char* pB0 = lds + 32768 + (wc * 32 + l15) * 128 + ((kgrp) ^ xlo) * 16;
    const char* pB1 = lds + 32768 + (wc * 32 + l15) * 128 + ((4 + kgrp) ^ xlo) * 16;

    // acc quadrants: 0=(0,0) 1=(0,1) 2=(1,1) 3=(1,0)  (mq,nq)
    f32x4 acc[4][4][2];
#pragma unroll
    for (int q = 0; q < 4; ++q)
#pragma unroll
        for (int m = 0; m < 4; ++m)
#pragma unroll
            for (int n = 0; n < 2; ++n)
                acc[q][m][n] = (f32x4){0.f, 0.f, 0.f, 0.f};

    // Prologue pair-stream (FIFO matches steady state):
    //  {Alo(0),Blo(0)}  [W1(-2) slot]
    //  {Ahi(0),Bhi(0)}  [W0(-1) slot]
    //  {Alo(1),Blo(1)}  [W1(-1) slot]
    STAGE(A, sA_lo[0], dst0);                 STAGE(A, sA_lo[1], dst1);
    STAGE(B, sB_lo[0], 32768 + dst0);         STAGE(B, sB_lo[1], 32768 + dst1);
    STAGE(A, sA_hi[0], 16384 + dst0);         STAGE(A, sA_hi[1], 16384 + dst1);
    STAGE(B, sB_hi[0], 49152 + dst0);         STAGE(B, sB_hi[1], 49152 + dst1);
    STAGE(A, sA_lo[0] + 64, 65536 + dst0);    STAGE(A, sA_lo[1] + 64, 65536 + dst1);
    STAGE(B, sB_lo[0] + 64, 98304 + dst0);    STAGE(B, sB_lo[1] + 64, 98304 + dst1);
    asm volatile("s_waitcnt vmcnt(8)" ::: "memory"); // confirms {Alo,Blo}(0)
    __builtin_amdgcn_s_barrier();

    for (int t = 0; t < NT; t += 2) {
        tile_body<0>(t,     acc, A, B, lds, sA_lo, sA_hi, sB_lo, sB_hi,
                     dst0, dst1, pA0, pA1, pB0, pB1);
        tile_body<1>(t + 1, acc, A, B, lds, sA_lo, sA_hi, sB_lo, sB_hi,
                     dst0, dst1, pA0, pA1, pB0, pB1);
    }

    // Epilogue (C/D layout: col = lane&15, row = (lane>>4)*4 + reg).
    // Nontemporal: C written once, never re-read -> don't churn L3.
#pragma unroll
    for (int q = 0; q < 4; ++q) {
        const int mqe = q >> 1;
        const int nqe = (q == 1 || q == 2) ? 1 : 0;
#pragma unroll
        for (int n = 0; n < 2; ++n) {
            const int col = n0 + nqe * 128 + wc * 32 + n * 16 + l15;
            const float bval = bias[col];
#pragma unroll
            for (int m = 0; m < 4; ++m) {
                const int row = m0 + mqe * 128 + wr * 64 + m * 16 + kgrp * 4;
#pragma unroll
                for (int r = 0; r < 4; ++r)
                    __builtin_nontemporal_store(acc[q][m][n][r] + bval,
                        &C[(size_t)(row + r) * N_DIM + col]);
            }
        }
    }
}

// ---------------------------------------------------------------------------
extern "C" void kernel_launch(void* const* d_in, const int* in_sizes, int n_in,
                              void* d_out, int out_size, void* d_ws, size_t ws_size,
                              hipStream_t stream)
{
    const float* x      = (const float*)d_in[0];  // [4,2048,4096] f32
    const int*   codes  = (const int*)d_in[1];    // [704512,64] i32
    const float* absmax = (const float*)d_in[2];  // [704512] f32
    const float* bias   = (const float*)d_in[3];  // [11008] f32
    float* out = (float*)d_out;                   // [4,2048,11008] f32

    const size_t w_bytes = (size_t)N_DIM * K_DIM * sizeof(__hip_bfloat16);
    const size_t x_bytes = (size_t)M_DIM * K_DIM * sizeof(__hip_bfloat16);
    if (ws_size < w_bytes + x_bytes) {
        fprintf(stderr, "kernel_launch: ws_size=%zu < needed %zu\n",
                ws_size, w_bytes + x_bytes);
        return;
    }
    __hip_bfloat16* wbf = (__hip_bfloat16*)d_ws;
    __hip_bfloat16* xbf = (__hip_bfloat16*)((char*)d_ws + w_bytes);

    // Allow 128 KiB dynamic LDS (idempotent host-side call; capture-safe).
    hipFuncSetAttribute((const void*)gemm_bf16_8phase,
                        hipFuncAttributeMaxDynamicSharedMemorySize, 131072);

    fp4_dequant_kernel<<<dim3(22016), dim3(256), 0, stream>>>(codes, absmax, wbf);
    f32_to_bf16_kernel<<<dim3(16384), dim3(256), 0, stream>>>(x, xbf);
    gemm_bf16_8phase<<<dim3(NWG), dim3(512), 131072, stream>>>(xbf, wbf, bias, out);
}